// Round 2
// baseline (986.791 us; speedup 1.0000x reference)
//
#include <hip/hip_runtime.h>
#include <hip/hip_bf16.h>
#include <math.h>

#define NT   65536      // total nodes (32 graphs * 2048)
#define NPGC 2048       // nodes per graph
#define NG   32         // graphs
#define NE   524288     // edges
#define HID  128

__device__ __forceinline__ float bf2f(unsigned short u) {
    union { unsigned int i; float f; } v; v.i = ((unsigned int)u) << 16; return v.f;
}
__device__ __forceinline__ unsigned short f2bf(float f) {
    union { float f; unsigned int i; } v; v.f = f;
    unsigned int x = v.i;
    return (unsigned short)((x + 0x7fffu + ((x >> 16) & 1u)) >> 16);
}

// ---------- dtype detection: bf16 vs fp32 ----------
// bf16 N(0,1) data: every ushort has a sane exponent. fp32 data read as
// ushorts: low halves are random mantissa bits -> ~38% insane exponents.
__global__ void k_detect(const unsigned short* __restrict__ x, int* __restrict__ flag) {
    __shared__ int cnt;
    if (threadIdx.x == 0) cnt = 0;
    __syncthreads();
    int sane = 0;
#pragma unroll
    for (int j = 0; j < 16; ++j) {
        unsigned short u = x[threadIdx.x * 16 + j];
        int e = (u >> 7) & 0xFF;
        if (e > 0x60 && e < 0xA0) sane++;
    }
    atomicAdd(&cnt, sane);
    __syncthreads();
    if (threadIdx.x == 0) *flag = (cnt > 3686) ? 1 : 0;   // >90% of 4096
}

// ---------- weight conversion: (bf16|f32) -> f32 scratch ----------
struct CvtDesc { const void* src[22]; int n[22]; int off[22]; };

__global__ void k_cvt(CvtDesc d, float* __restrict__ wts, const int* __restrict__ flag) {
    int t = blockIdx.y;
    int n = d.n[t];
    bool isbf = (*flag != 0);
    const unsigned short* sb = (const unsigned short*)d.src[t];
    const float* sf = (const float*)d.src[t];
    float* o = wts + d.off[t];
    for (int i = blockIdx.x * blockDim.x + threadIdx.x; i < n; i += gridDim.x * blockDim.x)
        o[i] = isbf ? bf2f(sb[i]) : sf[i];
}

// ---------- load x -> f32 ----------
__global__ void k_load_x(const void* __restrict__ x, float* __restrict__ out,
                         const int* __restrict__ flag, int n4) {
    int i = blockIdx.x * blockDim.x + threadIdx.x;
    if (i >= n4) return;
    if (*flag) {
        ushort4 v = ((const ushort4*)x)[i];
        float4 o;
        o.x = bf2f(v.x); o.y = bf2f(v.y); o.z = bf2f(v.z); o.w = bf2f(v.w);
        ((float4*)out)[i] = o;
    } else {
        ((float4*)out)[i] = ((const float4*)x)[i];
    }
}

__global__ void k_init_nm(float* __restrict__ nm) {
    int i = blockIdx.x * blockDim.x + threadIdx.x;
    if (i < NT) nm[i] = 1.0f;
}

// ---------- CSR build (by dst) ----------
__global__ void k_hist(const int* __restrict__ dst, int* __restrict__ cnt) {
    int e = blockIdx.x * blockDim.x + threadIdx.x;
    if (e < NE) atomicAdd(&cnt[dst[e]], 1);
}

__global__ void k_scan1(const int* __restrict__ cnt, int* __restrict__ rp, int* __restrict__ bsum) {
    __shared__ int s[256];
    int t = threadIdx.x;
    int i = blockIdx.x * 256 + t;
    int v = cnt[i];
    s[t] = v;
    __syncthreads();
    for (int off = 1; off < 256; off <<= 1) {
        int a = (t >= off) ? s[t - off] : 0;
        __syncthreads();
        s[t] += a;
        __syncthreads();
    }
    rp[i] = s[t] - v;
    if (t == 255) bsum[blockIdx.x] = s[255];
}

__global__ void k_scan2(const int* __restrict__ bsum, int* __restrict__ boff) {
    __shared__ int s[256];
    int t = threadIdx.x;
    int v = bsum[t];
    s[t] = v;
    __syncthreads();
    for (int off = 1; off < 256; off <<= 1) {
        int a = (t >= off) ? s[t - off] : 0;
        __syncthreads();
        s[t] += a;
        __syncthreads();
    }
    boff[t] = s[t] - v;
}

__global__ void k_scan3(int* __restrict__ rp, const int* __restrict__ boff) {
    int i = blockIdx.x * 256 + threadIdx.x;
    rp[i] += boff[i >> 8];
    if (i == 0) rp[NT] = NE;
}

__global__ void k_scatter(const int* __restrict__ src, const int* __restrict__ dst,
                          const int* __restrict__ rp, int* __restrict__ fill, int* __restrict__ col) {
    int e = blockIdx.x * blockDim.x + threadIdx.x;
    if (e < NE) {
        int d = dst[e];
        int p = rp[d] + atomicAdd(&fill[d], 1);
        col[p] = src[e];
    }
}

// ---------- mean aggregation ----------
__global__ void k_aggregate(const float* __restrict__ h, const float* __restrict__ nm,
                            const int* __restrict__ rp, const int* __restrict__ col,
                            float* __restrict__ m) {
    int tid = threadIdx.x;
    int node = blockIdx.x * 8 + (tid >> 5);
    int f = (tid & 31) * 4;
    int beg = rp[node], end = rp[node + 1];
    float ax = 0.f, ay = 0.f, az = 0.f, aw = 0.f, cnt = 0.f;
    for (int e = beg; e < end; ++e) {
        int s = col[e];
        float4 v = *(const float4*)&h[s * HID + f];
        ax += v.x; ay += v.y; az += v.z; aw += v.w;
        cnt += nm[s];
    }
    float inv = 1.0f / fmaxf(cnt, 1.0f);
    float4 o; o.x = ax * inv; o.y = ay * inv; o.z = az * inv; o.w = aw * inv;
    *(float4*)&m[node * HID + f] = o;
}

// ---------- fused SAGE linear: out = relu(m@Wl + bl + h@Wr) * nm ----------
__global__ void k_sage_gemm(const float* __restrict__ m, const float* __restrict__ h,
                            const float* __restrict__ Wl, const float* __restrict__ bl,
                            const float* __restrict__ Wr, const float* __restrict__ nm,
                            float* __restrict__ out) {
    int tid = threadIdx.x;
    int c = (tid & 31) * 4;
    int r = tid >> 5;
    int n0 = blockIdx.x * 64;
    float acc[8][4];
    float4 b4 = *(const float4*)&bl[c];
#pragma unroll
    for (int i = 0; i < 8; ++i) { acc[i][0] = b4.x; acc[i][1] = b4.y; acc[i][2] = b4.z; acc[i][3] = b4.w; }

    for (int f = 0; f < HID; f += 4) {
        float wl[4][4], wr[4][4];
#pragma unroll
        for (int v = 0; v < 4; ++v) {
            float4 a = *(const float4*)&Wl[(f + v) * HID + c];
            float4 b = *(const float4*)&Wr[(f + v) * HID + c];
            wl[v][0] = a.x; wl[v][1] = a.y; wl[v][2] = a.z; wl[v][3] = a.w;
            wr[v][0] = b.x; wr[v][1] = b.y; wr[v][2] = b.z; wr[v][3] = b.w;
        }
#pragma unroll
        for (int i = 0; i < 8; ++i) {
            int node = n0 + r + i * 8;
            float4 m4 = *(const float4*)&m[node * HID + f];
            float4 h4 = *(const float4*)&h[node * HID + f];
            float mv[4] = { m4.x, m4.y, m4.z, m4.w };
            float hv[4] = { h4.x, h4.y, h4.z, h4.w };
#pragma unroll
            for (int v = 0; v < 4; ++v)
#pragma unroll
                for (int u = 0; u < 4; ++u)
                    acc[i][u] += mv[v] * wl[v][u] + hv[v] * wr[v][u];
        }
    }
#pragma unroll
    for (int i = 0; i < 8; ++i) {
        int node = n0 + r + i * 8;
        float s = nm[node];
        float4 o;
        o.x = fmaxf(acc[i][0], 0.f) * s;
        o.y = fmaxf(acc[i][1], 0.f) * s;
        o.z = fmaxf(acc[i][2], 0.f) * s;
        o.w = fmaxf(acc[i][3], 0.f) * s;
        *(float4*)&out[node * HID + c] = o;
    }
}

// ---------- per-node dots with Prel / Proot ----------
__global__ void k_node_dots(const float* __restrict__ h, const float* __restrict__ Prel,
                            const float* __restrict__ Proot,
                            float* __restrict__ q, float* __restrict__ r) {
    int lane = threadIdx.x & 63;
    int node = blockIdx.x * 4 + (threadIdx.x >> 6);
    float h0 = h[node * HID + lane];
    float h1 = h[node * HID + 64 + lane];
    float qv = h0 * Prel[lane] + h1 * Prel[64 + lane];
    float rv = h0 * Proot[lane] + h1 * Proot[64 + lane];
    for (int o = 32; o > 0; o >>= 1) {
        qv += __shfl_down(qv, o, 64);
        rv += __shfl_down(rv, o, 64);
    }
    if (lane == 0) { q[node] = qv; r[node] = rv; }
}

// ---------- score = segsum(q[src]) + r + prb ----------
__global__ void k_score(const float* __restrict__ q, const float* __restrict__ r,
                        const float* __restrict__ prb,
                        const int* __restrict__ rp, const int* __restrict__ col,
                        float* __restrict__ score) {
    int n = blockIdx.x * 256 + threadIdx.x;
    int beg = rp[n], end = rp[n + 1];
    float s = 0.f;
    for (int e = beg; e < end; ++e) s += q[col[e]];
    score[n] = s + r[n] + prb[0];
}

// ---------- per-graph top-k via bitonic sort ----------
__global__ void __launch_bounds__(1024) k_topk(const float* __restrict__ score,
                                               float* __restrict__ nm, int k) {
    __shared__ unsigned long long keys[NPGC];
    __shared__ unsigned char msk[NPGC];
    int tid = threadIdx.x;
    int base = blockIdx.x * NPGC;
    for (int j = tid; j < NPGC; j += 1024) {
        float sc = (nm[base + j] > 0.f) ? score[base + j] : -1e30f;
        unsigned int u = __float_as_uint(sc);
        u = (u & 0x80000000u) ? ~u : (u | 0x80000000u);
        keys[j] = ((unsigned long long)u << 32) | (unsigned long long)(NPGC - 1 - j);
        msk[j] = 0;
    }
    for (int size = 2; size <= NPGC; size <<= 1) {
        for (int stride = size >> 1; stride > 0; stride >>= 1) {
            __syncthreads();
            for (int t = tid; t < NPGC; t += 1024) {
                int partner = t ^ stride;
                if (partner > t) {
                    bool desc = ((t & size) == 0);
                    unsigned long long a = keys[t], b = keys[partner];
                    if ((a < b) == desc) { keys[t] = b; keys[partner] = a; }
                }
            }
        }
    }
    __syncthreads();
    for (int j = tid; j < NPGC; j += 1024) {
        if (j < k) {
            int idx = NPGC - 1 - (int)(keys[j] & 0xFFFFFFFFull);
            msk[idx] = 1;
        }
    }
    __syncthreads();
    for (int j = tid; j < NPGC; j += 1024)
        nm[base + j] = msk[j] ? 1.0f : 0.0f;
}

// ---------- h *= tanh(score) * nm ----------
__global__ void k_apply(float* __restrict__ h, const float* __restrict__ score,
                        const float* __restrict__ nm) {
    int i = blockIdx.x * 256 + threadIdx.x;
    int node = i >> 5;
    float t = tanhf(score[node]) * nm[node];
    float4 v = ((float4*)h)[i];
    v.x *= t; v.y *= t; v.z *= t; v.w *= t;
    ((float4*)h)[i] = v;
}

// ---------- per-graph mean ----------
__global__ void k_gsum(const float* __restrict__ h, const float* __restrict__ nm,
                       float* __restrict__ g, float* __restrict__ gcnt) {
    int b = blockIdx.x;
    int graph = b >> 3, part = b & 7;
    int f = threadIdx.x & 127, sub = threadIdx.x >> 7;
    int nbase = graph * NPGC + part * 256 + sub * 128;
    float acc = 0.f, cnt = 0.f;
    for (int n = 0; n < 128; ++n) {
        acc += h[(nbase + n) * HID + f];
        cnt += nm[nbase + n];
    }
    atomicAdd(&g[graph * HID + f], acc);
    if (f == 0) atomicAdd(&gcnt[graph], cnt);
}

__global__ void k_gdiv(float* __restrict__ g, const float* __restrict__ gcnt) {
    int i = blockIdx.x * 256 + threadIdx.x;
    if (i < NG * HID) g[i] /= fmaxf(gcnt[i >> 7], 1.0f);
}

// ---------- MLP head + log_softmax ----------
__global__ void k_mlp(const float* __restrict__ g, const float* __restrict__ W5,
                      const float* __restrict__ b5, const float* __restrict__ W6,
                      const float* __restrict__ b6, void* __restrict__ out,
                      const int* __restrict__ flag) {
    __shared__ float g5[64];
    __shared__ float ls[2];
    int graph = blockIdx.x, j = threadIdx.x;
    float acc = b5[j];
    for (int f = 0; f < HID; ++f)
        acc += g[graph * HID + f] * W5[f * 64 + j];
    g5[j] = fmaxf(acc, 0.f);
    __syncthreads();
    if (j < 2) {
        float l = b6[j];
        for (int t = 0; t < 64; ++t) l += g5[t] * W6[t * 2 + j];
        ls[j] = l;
    }
    __syncthreads();
    if (j == 0) {
        float a = ls[0], b = ls[1];
        float mx = fmaxf(a, b);
        float lse = mx + logf(expf(a - mx) + expf(b - mx));
        if (*flag) {
            ((unsigned short*)out)[graph * 2 + 0] = f2bf(a - lse);
            ((unsigned short*)out)[graph * 2 + 1] = f2bf(b - lse);
        } else {
            ((float*)out)[graph * 2 + 0] = a - lse;
            ((float*)out)[graph * 2 + 1] = b - lse;
        }
    }
}

extern "C" void kernel_launch(void* const* d_in, const int* in_sizes, int n_in,
                              void* d_out, int out_size, void* d_ws, size_t ws_size,
                              hipStream_t stream) {
    const void* x    = d_in[0];
    const int*  ei   = (const int*)d_in[1];
    const int*  srcE = ei;
    const int*  dstE = ei + NE;

    char* ws = (char*)d_ws;
    float* hA    = (float*)(ws + 0);
    float* hB    = (float*)(ws + 33554432);
    float* mb    = (float*)(ws + 67108864);
    float* q     = (float*)(ws + 100663296);
    float* r     = (float*)(ws + 100925440);
    float* score = (float*)(ws + 101187584);
    float* nm    = (float*)(ws + 101449728);
    int*   rowc  = (int*)  (ws + 101711872);
    int*   rp    = (int*)  (ws + 101974016);
    int*   bsum  = (int*)  (ws + 102236416);
    int*   boff  = (int*)  (ws + 102237440);
    int*   fill  = (int*)  (ws + 102238464);
    int*   col   = (int*)  (ws + 102500608);
    float* g     = (float*)(ws + 104597760);
    // gcnt contiguous after g at 104614144
    float* gcnt  = (float*)(ws + 104614144);
    int*   flag  = (int*)  (ws + 104615936);
    float* wts   = (float*)(ws + 104616960);
    (void)in_sizes; (void)n_in; (void)out_size; (void)ws_size;

    // converted-weight offsets (floats)
    const int O_Wl1 = 0,      O_bl1 = 16384,  O_Wr1 = 16512;
    const int O_Wl2 = 32896,  O_bl2 = 49280,  O_Wr2 = 49408;
    const int O_Wl3 = 65792,  O_bl3 = 82176,  O_Wr3 = 82304;
    const int O_Wl4 = 98688,  O_bl4 = 115072, O_Wr4 = 115200;
    const int O_Pr1 = 131584, O_pb1 = 131712, O_Po1 = 131713;
    const int O_Pr2 = 131841, O_pb2 = 131969, O_Po2 = 131970;
    const int O_W5  = 132098, O_b5  = 140290, O_W6 = 140354, O_b6 = 140482;

    CvtDesc d;
    const int srcIdx[22] = {4,5,6,7,8,9,10,11,12,13,14,15,16,17,18,19,20,21,22,23,24,25};
    const int nelems[22] = {16384,128,16384, 16384,128,16384, 16384,128,16384, 16384,128,16384,
                            128,1,128, 128,1,128, 8192,64,128,2};
    const int offs[22]   = {O_Wl1,O_bl1,O_Wr1, O_Wl2,O_bl2,O_Wr2, O_Wl3,O_bl3,O_Wr3, O_Wl4,O_bl4,O_Wr4,
                            O_Pr1,O_pb1,O_Po1, O_Pr2,O_pb2,O_Po2, O_W5,O_b5,O_W6,O_b6};
    for (int i = 0; i < 22; ++i) { d.src[i] = d_in[srcIdx[i]]; d.n[i] = nelems[i]; d.off[i] = offs[i]; }

    hipMemsetAsync(rowc, 0, NT * 4, stream);
    hipMemsetAsync(fill, 0, NT * 4, stream);
    hipMemsetAsync(g, 0, (NG * HID + NG + 512) * 4, stream);  // g + gcnt region

    k_detect <<<1, 256, 0, stream>>>((const unsigned short*)x, flag);
    k_cvt    <<<dim3(64, 22), 256, 0, stream>>>(d, wts, flag);
    k_load_x <<<8192, 256, 0, stream>>>(x, hA, flag, NT * HID / 4);
    k_init_nm<<<256, 256, 0, stream>>>(nm);

    k_hist   <<<2048, 256, 0, stream>>>(dstE, rowc);
    k_scan1  <<<256, 256, 0, stream>>>(rowc, rp, bsum);
    k_scan2  <<<1, 256, 0, stream>>>(bsum, boff);
    k_scan3  <<<256, 256, 0, stream>>>(rp, boff);
    k_scatter<<<2048, 256, 0, stream>>>(srcE, dstE, rp, fill, col);

    // layer 1: hA -> hB
    k_aggregate<<<8192, 256, 0, stream>>>(hA, nm, rp, col, mb);
    k_sage_gemm<<<1024, 256, 0, stream>>>(mb, hA, wts + O_Wl1, wts + O_bl1, wts + O_Wr1, nm, hB);
    // layer 2: hB -> hA
    k_aggregate<<<8192, 256, 0, stream>>>(hB, nm, rp, col, mb);
    k_sage_gemm<<<1024, 256, 0, stream>>>(mb, hB, wts + O_Wl2, wts + O_bl2, wts + O_Wr2, nm, hA);

    // pool 1 (k = 1024)
    k_node_dots<<<16384, 256, 0, stream>>>(hA, wts + O_Pr1, wts + O_Po1, q, r);
    k_score    <<<256, 256, 0, stream>>>(q, r, wts + O_pb1, rp, col, score);
    k_topk     <<<32, 1024, 0, stream>>>(score, nm, 1024);
    k_apply    <<<8192, 256, 0, stream>>>(hA, score, nm);

    // layer 3: hA -> hB
    k_aggregate<<<8192, 256, 0, stream>>>(hA, nm, rp, col, mb);
    k_sage_gemm<<<1024, 256, 0, stream>>>(mb, hA, wts + O_Wl3, wts + O_bl3, wts + O_Wr3, nm, hB);
    // layer 4: hB -> hA
    k_aggregate<<<8192, 256, 0, stream>>>(hB, nm, rp, col, mb);
    k_sage_gemm<<<1024, 256, 0, stream>>>(mb, hB, wts + O_Wl4, wts + O_bl4, wts + O_Wr4, nm, hA);

    // pool 2 (k = 512)
    k_node_dots<<<16384, 256, 0, stream>>>(hA, wts + O_Pr2, wts + O_Po2, q, r);
    k_score    <<<256, 256, 0, stream>>>(q, r, wts + O_pb2, rp, col, score);
    k_topk     <<<32, 1024, 0, stream>>>(score, nm, 512);
    k_apply    <<<8192, 256, 0, stream>>>(hA, score, nm);

    // readout
    k_gsum<<<256, 256, 0, stream>>>(hA, nm, g, gcnt);
    k_gdiv<<<16, 256, 0, stream>>>(g, gcnt);
    k_mlp <<<32, 64, 0, stream>>>(g, wts + O_W5, wts + O_b5, wts + O_W6, wts + O_b6, d_out, flag);
}

// Round 3
// 582.547 us; speedup vs baseline: 1.6939x; 1.6939x over previous
//
#include <hip/hip_runtime.h>
#include <hip/hip_bf16.h>
#include <math.h>

#define NT   65536      // total nodes (32 graphs * 2048)
#define NPGC 2048       // nodes per graph
#define NG   32         // graphs
#define NE   524288     // edges
#define HID  128

typedef short short8 __attribute__((ext_vector_type(8)));
typedef float f32x4  __attribute__((ext_vector_type(4)));

__device__ __forceinline__ float bf2f(unsigned short u) {
    union { unsigned int i; float f; } v; v.i = ((unsigned int)u) << 16; return v.f;
}
__device__ __forceinline__ unsigned short f2bf(float f) {
    union { float f; unsigned int i; } v; v.f = f;
    unsigned int x = v.i;
    return (unsigned short)((x + 0x7fffu + ((x >> 16) & 1u)) >> 16);
}

// ---------- dtype detection: bf16 vs fp32 ----------
__global__ void k_detect(const unsigned short* __restrict__ x, int* __restrict__ flag) {
    __shared__ int cnt;
    if (threadIdx.x == 0) cnt = 0;
    __syncthreads();
    int sane = 0;
#pragma unroll
    for (int j = 0; j < 16; ++j) {
        unsigned short u = x[threadIdx.x * 16 + j];
        int e = (u >> 7) & 0xFF;
        if (e > 0x60 && e < 0xA0) sane++;
    }
    atomicAdd(&cnt, sane);
    __syncthreads();
    if (threadIdx.x == 0) *flag = (cnt > 3686) ? 1 : 0;
}

// ---------- weight conversion: (bf16|f32) -> f32 scratch ----------
struct CvtDesc { const void* src[22]; int n[22]; int off[22]; };

__global__ void k_cvt(CvtDesc d, float* __restrict__ wts, const int* __restrict__ flag) {
    int t = blockIdx.y;
    int n = d.n[t];
    bool isbf = (*flag != 0);
    const unsigned short* sb = (const unsigned short*)d.src[t];
    const float* sf = (const float*)d.src[t];
    float* o = wts + d.off[t];
    for (int i = blockIdx.x * blockDim.x + threadIdx.x; i < n; i += gridDim.x * blockDim.x)
        o[i] = isbf ? bf2f(sb[i]) : sf[i];
}

// ---------- pack SAGE weights into MFMA fragment order, bf16 hi/lo ----------
// W_L = [Wl_L (128x128) ; Wr_L (128x128)]  (256 x 128, k-major)
// Wpack[L][p][ct][ks][lane][j]: k = ks*32 + (lane>>4)*8 + j, col = ct*16 + (lane&15)
__global__ void k_packW(const float* __restrict__ wts, int4 oWl, int4 oWr,
                        unsigned short* __restrict__ Wpack) {
    int idx = blockIdx.x * 256 + threadIdx.x;   // 4*8*8*64*8 / ... per (L,ct,ks,lane,j)
    if (idx >= 4 * 8 * 8 * 64 * 8) return;
    int L    = idx >> 15;
    int rem  = idx & 32767;
    int ct   = rem >> 12;
    int rem2 = rem & 4095;
    int ks   = rem2 >> 9;
    int rem3 = rem2 & 511;
    int lane = rem3 >> 3;
    int j    = rem3 & 7;
    int k   = ks * 32 + (lane >> 4) * 8 + j;
    int col = ct * 16 + (lane & 15);
    int ol = (L == 0) ? oWl.x : (L == 1) ? oWl.y : (L == 2) ? oWl.z : oWl.w;
    int orr = (L == 0) ? oWr.x : (L == 1) ? oWr.y : (L == 2) ? oWr.z : oWr.w;
    float w = (k < 128) ? wts[ol + k * 128 + col] : wts[orr + (k - 128) * 128 + col];
    unsigned short hi = f2bf(w);
    unsigned short lo = f2bf(w - bf2f(hi));
    int base = L * 65536 + (ct * 8 + ks) * 512 + lane * 8 + j;
    Wpack[base]         = hi;          // plane 0
    Wpack[base + 32768] = lo;          // plane 1
}

// ---------- load x -> f32 ----------
__global__ void k_load_x(const void* __restrict__ x, float* __restrict__ out,
                         const int* __restrict__ flag, int n4) {
    int i = blockIdx.x * blockDim.x + threadIdx.x;
    if (i >= n4) return;
    if (*flag) {
        ushort4 v = ((const ushort4*)x)[i];
        float4 o;
        o.x = bf2f(v.x); o.y = bf2f(v.y); o.z = bf2f(v.z); o.w = bf2f(v.w);
        ((float4*)out)[i] = o;
    } else {
        ((float4*)out)[i] = ((const float4*)x)[i];
    }
}

__global__ void k_init_nm(float* __restrict__ nm) {
    int i = blockIdx.x * blockDim.x + threadIdx.x;
    if (i < NT) nm[i] = 1.0f;
}

// ---------- CSR build (by dst) ----------
__global__ void k_hist(const int* __restrict__ dst, int* __restrict__ cnt) {
    int e = blockIdx.x * blockDim.x + threadIdx.x;
    if (e < NE) atomicAdd(&cnt[dst[e]], 1);
}

__global__ void k_scan1(const int* __restrict__ cnt, int* __restrict__ rp, int* __restrict__ bsum) {
    __shared__ int s[256];
    int t = threadIdx.x;
    int i = blockIdx.x * 256 + t;
    int v = cnt[i];
    s[t] = v;
    __syncthreads();
    for (int off = 1; off < 256; off <<= 1) {
        int a = (t >= off) ? s[t - off] : 0;
        __syncthreads();
        s[t] += a;
        __syncthreads();
    }
    rp[i] = s[t] - v;
    if (t == 255) bsum[blockIdx.x] = s[255];
}

__global__ void k_scan2(const int* __restrict__ bsum, int* __restrict__ boff) {
    __shared__ int s[256];
    int t = threadIdx.x;
    int v = bsum[t];
    s[t] = v;
    __syncthreads();
    for (int off = 1; off < 256; off <<= 1) {
        int a = (t >= off) ? s[t - off] : 0;
        __syncthreads();
        s[t] += a;
        __syncthreads();
    }
    boff[t] = s[t] - v;
}

__global__ void k_scan3(int* __restrict__ rp, const int* __restrict__ boff) {
    int i = blockIdx.x * 256 + threadIdx.x;
    rp[i] += boff[i >> 8];
    if (i == 0) rp[NT] = NE;
}

__global__ void k_scatter(const int* __restrict__ src, const int* __restrict__ dst,
                          const int* __restrict__ rp, int* __restrict__ fill, int* __restrict__ col) {
    int e = blockIdx.x * blockDim.x + threadIdx.x;
    if (e < NE) {
        int d = dst[e];
        int p = rp[d] + atomicAdd(&fill[d], 1);
        col[p] = src[e];
    }
}

// ---------- mean aggregation ----------
__global__ void k_aggregate(const float* __restrict__ h, const float* __restrict__ nm,
                            const int* __restrict__ rp, const int* __restrict__ col,
                            float* __restrict__ m) {
    int tid = threadIdx.x;
    int node = blockIdx.x * 8 + (tid >> 5);
    int f = (tid & 31) * 4;
    int beg = rp[node], end = rp[node + 1];
    float ax = 0.f, ay = 0.f, az = 0.f, aw = 0.f, cnt = 0.f;
    for (int e = beg; e < end; ++e) {
        int s = col[e];
        float4 v = *(const float4*)&h[s * HID + f];
        ax += v.x; ay += v.y; az += v.z; aw += v.w;
        cnt += nm[s];
    }
    float inv = 1.0f / fmaxf(cnt, 1.0f);
    float4 o; o.x = ax * inv; o.y = ay * inv; o.z = az * inv; o.w = aw * inv;
    *(float4*)&m[node * HID + f] = o;
}

// ---------- MFMA SAGE linear: out = relu([m|h]@[Wl;Wr] + bl) * nm ----------
// split-bf16: A ~ Ahi + Alo; C = Ahi*Whi + Alo*Whi + Ahi*Wlo (err ~2^-16 rel)
__device__ __forceinline__ int lds_sw(int node, int k) {
    // [64][256] ushort row-major with 16B-granule XOR swizzle to spread banks
    int g = k >> 3;
    int go = g ^ (node & 7);
    return node * 256 + go * 8 + (k & 7);
}

__global__ void __launch_bounds__(256) k_sage_mfma(
    const float* __restrict__ m, const float* __restrict__ h,
    const unsigned short* __restrict__ Wp,   // layer's packed weights (hi plane then lo plane)
    const float* __restrict__ bl, const float* __restrict__ nm,
    float* __restrict__ out)
{
    __shared__ unsigned short Ahi[64 * 256];
    __shared__ unsigned short Alo[64 * 256];
    int tid = threadIdx.x;
    int n0 = blockIdx.x * 64;

    // stage A = [m | h] tile as hi/lo bf16
#pragma unroll
    for (int i = 0; i < 16; ++i) {
        int f4 = i * 256 + tid;
        int node = f4 >> 6;
        int sub = f4 & 63;              // 0..31 -> m, 32..63 -> h
        int k = sub * 4;                // K index 0..255
        int feat = (sub & 31) * 4;
        const float* base = (sub < 32) ? m : h;
        float4 v = *(const float4*)&base[(size_t)(n0 + node) * HID + feat];
        ushort4 hi4, lo4;
        hi4.x = f2bf(v.x); lo4.x = f2bf(v.x - bf2f(hi4.x));
        hi4.y = f2bf(v.y); lo4.y = f2bf(v.y - bf2f(hi4.y));
        hi4.z = f2bf(v.z); lo4.z = f2bf(v.z - bf2f(hi4.z));
        hi4.w = f2bf(v.w); lo4.w = f2bf(v.w - bf2f(hi4.w));
        int a = lds_sw(node, k);
        *(ushort4*)&Ahi[a] = hi4;
        *(ushort4*)&Alo[a] = lo4;
    }
    __syncthreads();

    int lane = tid & 63, w = tid >> 6;
    int lrow = lane & 15, quad = lane >> 4;
    f32x4 acc[4][2] = {};

    for (int ks = 0; ks < 8; ++ks) {
        short8 bh[2], blo[2];
#pragma unroll
        for (int c = 0; c < 2; ++c) {
            int ct = 2 * w + c;
            bh[c]  = *(const short8*)&Wp[(ct * 8 + ks) * 512 + lane * 8];
            blo[c] = *(const short8*)&Wp[32768 + (ct * 8 + ks) * 512 + lane * 8];
        }
        int kb = ks * 32 + quad * 8;
#pragma unroll
        for (int st = 0; st < 4; ++st) {
            int a = lds_sw(st * 16 + lrow, kb);
            short8 ah = *(const short8*)&Ahi[a];
            short8 al = *(const short8*)&Alo[a];
#pragma unroll
            for (int c = 0; c < 2; ++c) {
                acc[st][c] = __builtin_amdgcn_mfma_f32_16x16x32_bf16(ah, bh[c],  acc[st][c], 0, 0, 0);
                acc[st][c] = __builtin_amdgcn_mfma_f32_16x16x32_bf16(al, bh[c],  acc[st][c], 0, 0, 0);
                acc[st][c] = __builtin_amdgcn_mfma_f32_16x16x32_bf16(ah, blo[c], acc[st][c], 0, 0, 0);
            }
        }
    }

    // epilogue: C/D layout col=lane&15, row=quad*4+reg
#pragma unroll
    for (int c = 0; c < 2; ++c) {
        int colg = (2 * w + c) * 16 + lrow;
        float bias = bl[colg];
#pragma unroll
        for (int st = 0; st < 4; ++st) {
#pragma unroll
            for (int r = 0; r < 4; ++r) {
                int node = n0 + st * 16 + quad * 4 + r;
                float val = fmaxf(acc[st][c][r] + bias, 0.f) * nm[node];
                out[(size_t)node * HID + colg] = val;
            }
        }
    }
}

// ---------- per-node dots with Prel / Proot ----------
__global__ void k_node_dots(const float* __restrict__ h, const float* __restrict__ Prel,
                            const float* __restrict__ Proot,
                            float* __restrict__ q, float* __restrict__ r) {
    int lane = threadIdx.x & 63;
    int node = blockIdx.x * 4 + (threadIdx.x >> 6);
    float h0 = h[node * HID + lane];
    float h1 = h[node * HID + 64 + lane];
    float qv = h0 * Prel[lane] + h1 * Prel[64 + lane];
    float rv = h0 * Proot[lane] + h1 * Proot[64 + lane];
    for (int o = 32; o > 0; o >>= 1) {
        qv += __shfl_down(qv, o, 64);
        rv += __shfl_down(rv, o, 64);
    }
    if (lane == 0) { q[node] = qv; r[node] = rv; }
}

// ---------- score = segsum(q[src]) + r + prb ----------
__global__ void k_score(const float* __restrict__ q, const float* __restrict__ r,
                        const float* __restrict__ prb,
                        const int* __restrict__ rp, const int* __restrict__ col,
                        float* __restrict__ score) {
    int n = blockIdx.x * 256 + threadIdx.x;
    int beg = rp[n], end = rp[n + 1];
    float s = 0.f;
    for (int e = beg; e < end; ++e) s += q[col[e]];
    score[n] = s + r[n] + prb[0];
}

// ---------- per-graph top-k via bitonic sort ----------
__global__ void __launch_bounds__(1024) k_topk(const float* __restrict__ score,
                                               float* __restrict__ nm, int k) {
    __shared__ unsigned long long keys[NPGC];
    __shared__ unsigned char msk[NPGC];
    int tid = threadIdx.x;
    int base = blockIdx.x * NPGC;
    for (int j = tid; j < NPGC; j += 1024) {
        float sc = (nm[base + j] > 0.f) ? score[base + j] : -1e30f;
        unsigned int u = __float_as_uint(sc);
        u = (u & 0x80000000u) ? ~u : (u | 0x80000000u);
        keys[j] = ((unsigned long long)u << 32) | (unsigned long long)(NPGC - 1 - j);
        msk[j] = 0;
    }
    for (int size = 2; size <= NPGC; size <<= 1) {
        for (int stride = size >> 1; stride > 0; stride >>= 1) {
            __syncthreads();
            for (int t = tid; t < NPGC; t += 1024) {
                int partner = t ^ stride;
                if (partner > t) {
                    bool desc = ((t & size) == 0);
                    unsigned long long a = keys[t], b = keys[partner];
                    if ((a < b) == desc) { keys[t] = b; keys[partner] = a; }
                }
            }
        }
    }
    __syncthreads();
    for (int j = tid; j < NPGC; j += 1024) {
        if (j < k) {
            int idx = NPGC - 1 - (int)(keys[j] & 0xFFFFFFFFull);
            msk[idx] = 1;
        }
    }
    __syncthreads();
    for (int j = tid; j < NPGC; j += 1024)
        nm[base + j] = msk[j] ? 1.0f : 0.0f;
}

// ---------- h *= tanh(score) * nm ----------
__global__ void k_apply(float* __restrict__ h, const float* __restrict__ score,
                        const float* __restrict__ nm) {
    int i = blockIdx.x * 256 + threadIdx.x;
    int node = i >> 5;
    float t = tanhf(score[node]) * nm[node];
    float4 v = ((float4*)h)[i];
    v.x *= t; v.y *= t; v.z *= t; v.w *= t;
    ((float4*)h)[i] = v;
}

// ---------- per-graph mean ----------
__global__ void k_gsum(const float* __restrict__ h, const float* __restrict__ nm,
                       float* __restrict__ g, float* __restrict__ gcnt) {
    int b = blockIdx.x;
    int graph = b >> 3, part = b & 7;
    int f = threadIdx.x & 127, sub = threadIdx.x >> 7;
    int nbase = graph * NPGC + part * 256 + sub * 128;
    float acc = 0.f, cnt = 0.f;
    for (int n = 0; n < 128; ++n) {
        acc += h[(nbase + n) * HID + f];
        cnt += nm[nbase + n];
    }
    atomicAdd(&g[graph * HID + f], acc);
    if (f == 0) atomicAdd(&gcnt[graph], cnt);
}

__global__ void k_gdiv(float* __restrict__ g, const float* __restrict__ gcnt) {
    int i = blockIdx.x * 256 + threadIdx.x;
    if (i < NG * HID) g[i] /= fmaxf(gcnt[i >> 7], 1.0f);
}

// ---------- MLP head + log_softmax ----------
__global__ void k_mlp(const float* __restrict__ g, const float* __restrict__ W5,
                      const float* __restrict__ b5, const float* __restrict__ W6,
                      const float* __restrict__ b6, void* __restrict__ out,
                      const int* __restrict__ flag) {
    __shared__ float g5[64];
    __shared__ float ls[2];
    int graph = blockIdx.x, j = threadIdx.x;
    float acc = b5[j];
    for (int f = 0; f < HID; ++f)
        acc += g[graph * HID + f] * W5[f * 64 + j];
    g5[j] = fmaxf(acc, 0.f);
    __syncthreads();
    if (j < 2) {
        float l = b6[j];
        for (int t = 0; t < 64; ++t) l += g5[t] * W6[t * 2 + j];
        ls[j] = l;
    }
    __syncthreads();
    if (j == 0) {
        float a = ls[0], b = ls[1];
        float mx = fmaxf(a, b);
        float lse = mx + logf(expf(a - mx) + expf(b - mx));
        if (*flag) {
            ((unsigned short*)out)[graph * 2 + 0] = f2bf(a - lse);
            ((unsigned short*)out)[graph * 2 + 1] = f2bf(b - lse);
        } else {
            ((float*)out)[graph * 2 + 0] = a - lse;
            ((float*)out)[graph * 2 + 1] = b - lse;
        }
    }
}

extern "C" void kernel_launch(void* const* d_in, const int* in_sizes, int n_in,
                              void* d_out, int out_size, void* d_ws, size_t ws_size,
                              hipStream_t stream) {
    const void* x    = d_in[0];
    const int*  ei   = (const int*)d_in[1];
    const int*  srcE = ei;
    const int*  dstE = ei + NE;

    char* ws = (char*)d_ws;
    float* hA    = (float*)(ws + 0);
    float* hB    = (float*)(ws + 33554432);
    float* mb    = (float*)(ws + 67108864);
    float* q     = (float*)(ws + 100663296);
    float* r     = (float*)(ws + 100925440);
    float* score = (float*)(ws + 101187584);
    float* nm    = (float*)(ws + 101449728);
    int*   rowc  = (int*)  (ws + 101711872);
    int*   rp    = (int*)  (ws + 101974016);
    int*   bsum  = (int*)  (ws + 102236416);
    int*   boff  = (int*)  (ws + 102237440);
    int*   fill  = (int*)  (ws + 102238464);
    int*   col   = (int*)  (ws + 102500608);
    float* g     = (float*)(ws + 104597760);
    float* gcnt  = (float*)(ws + 104614144);
    int*   flag  = (int*)  (ws + 104615936);
    float* wts   = (float*)(ws + 104616960);
    unsigned short* Wpack = (unsigned short*)(ws + 105179136);  // 512 KB
    (void)in_sizes; (void)n_in; (void)out_size; (void)ws_size;

    // converted-weight offsets (floats)
    const int O_Wl1 = 0,      O_bl1 = 16384,  O_Wr1 = 16512;
    const int O_Wl2 = 32896,  O_bl2 = 49280,  O_Wr2 = 49408;
    const int O_Wl3 = 65792,  O_bl3 = 82176,  O_Wr3 = 82304;
    const int O_Wl4 = 98688,  O_bl4 = 115072, O_Wr4 = 115200;
    const int O_Pr1 = 131584, O_pb1 = 131712, O_Po1 = 131713;
    const int O_Pr2 = 131841, O_pb2 = 131969, O_Po2 = 131970;
    const int O_W5  = 132098, O_b5  = 140290, O_W6 = 140354, O_b6 = 140482;

    CvtDesc d;
    const int srcIdx[22] = {4,5,6,7,8,9,10,11,12,13,14,15,16,17,18,19,20,21,22,23,24,25};
    const int nelems[22] = {16384,128,16384, 16384,128,16384, 16384,128,16384, 16384,128,16384,
                            128,1,128, 128,1,128, 8192,64,128,2};
    const int offs[22]   = {O_Wl1,O_bl1,O_Wr1, O_Wl2,O_bl2,O_Wr2, O_Wl3,O_bl3,O_Wr3, O_Wl4,O_bl4,O_Wr4,
                            O_Pr1,O_pb1,O_Po1, O_Pr2,O_pb2,O_Po2, O_W5,O_b5,O_W6,O_b6};
    for (int i = 0; i < 22; ++i) { d.src[i] = d_in[srcIdx[i]]; d.n[i] = nelems[i]; d.off[i] = offs[i]; }

    hipMemsetAsync(rowc, 0, NT * 4, stream);
    hipMemsetAsync(fill, 0, NT * 4, stream);
    hipMemsetAsync(g, 0, (NG * HID + NG + 512) * 4, stream);

    k_detect <<<1, 256, 0, stream>>>((const unsigned short*)x, flag);
    k_cvt    <<<dim3(64, 22), 256, 0, stream>>>(d, wts, flag);
    k_packW  <<<512, 256, 0, stream>>>(wts, make_int4(O_Wl1, O_Wl2, O_Wl3, O_Wl4),
                                       make_int4(O_Wr1, O_Wr2, O_Wr3, O_Wr4), Wpack);
    k_load_x <<<8192, 256, 0, stream>>>(x, hA, flag, NT * HID / 4);
    k_init_nm<<<256, 256, 0, stream>>>(nm);

    k_hist   <<<2048, 256, 0, stream>>>(dstE, rowc);
    k_scan1  <<<256, 256, 0, stream>>>(rowc, rp, bsum);
    k_scan2  <<<1, 256, 0, stream>>>(bsum, boff);
    k_scan3  <<<256, 256, 0, stream>>>(rp, boff);
    k_scatter<<<2048, 256, 0, stream>>>(srcE, dstE, rp, fill, col);

    // layer 1: hA -> hB
    k_aggregate<<<8192, 256, 0, stream>>>(hA, nm, rp, col, mb);
    k_sage_mfma<<<1024, 256, 0, stream>>>(mb, hA, Wpack + 0 * 65536, wts + O_bl1, nm, hB);
    // layer 2: hB -> hA
    k_aggregate<<<8192, 256, 0, stream>>>(hB, nm, rp, col, mb);
    k_sage_mfma<<<1024, 256, 0, stream>>>(mb, hB, Wpack + 1 * 65536, wts + O_bl2, nm, hA);

    // pool 1 (k = 1024)
    k_node_dots<<<16384, 256, 0, stream>>>(hA, wts + O_Pr1, wts + O_Po1, q, r);
    k_score    <<<256, 256, 0, stream>>>(q, r, wts + O_pb1, rp, col, score);
    k_topk     <<<32, 1024, 0, stream>>>(score, nm, 1024);
    k_apply    <<<8192, 256, 0, stream>>>(hA, score, nm);

    // layer 3: hA -> hB
    k_aggregate<<<8192, 256, 0, stream>>>(hA, nm, rp, col, mb);
    k_sage_mfma<<<1024, 256, 0, stream>>>(mb, hA, Wpack + 2 * 65536, wts + O_bl3, nm, hB);
    // layer 4: hB -> hA
    k_aggregate<<<8192, 256, 0, stream>>>(hB, nm, rp, col, mb);
    k_sage_mfma<<<1024, 256, 0, stream>>>(mb, hB, Wpack + 3 * 65536, wts + O_bl4, nm, hA);

    // pool 2 (k = 512)
    k_node_dots<<<16384, 256, 0, stream>>>(hA, wts + O_Pr2, wts + O_Po2, q, r);
    k_score    <<<256, 256, 0, stream>>>(q, r, wts + O_pb2, rp, col, score);
    k_topk     <<<32, 1024, 0, stream>>>(score, nm, 512);
    k_apply    <<<8192, 256, 0, stream>>>(hA, score, nm);

    // readout
    k_gsum<<<256, 256, 0, stream>>>(hA, nm, g, gcnt);
    k_gdiv<<<16, 256, 0, stream>>>(g, gcnt);
    k_mlp <<<32, 64, 0, stream>>>(g, wts + O_W5, wts + O_b5, wts + O_W6, wts + O_b6, d_out, flag);
}

// Round 4
// 533.781 us; speedup vs baseline: 1.8487x; 1.0914x over previous
//
#include <hip/hip_runtime.h>
#include <hip/hip_bf16.h>
#include <math.h>

#define NT   65536      // total nodes (32 graphs * 2048)
#define NPGC 2048       // nodes per graph
#define NG   32         // graphs
#define NE   524288     // edges
#define HID  128

typedef short short8 __attribute__((ext_vector_type(8)));
typedef float f32x4  __attribute__((ext_vector_type(4)));

__device__ __forceinline__ float bf2f(unsigned short u) {
    union { unsigned int i; float f; } v; v.i = ((unsigned int)u) << 16; return v.f;
}
__device__ __forceinline__ unsigned short f2bf(float f) {
    union { float f; unsigned int i; } v; v.f = f;
    unsigned int x = v.i;
    return (unsigned short)((x + 0x7fffu + ((x >> 16) & 1u)) >> 16);
}

// ---------- dtype detection: bf16 vs fp32 ----------
__global__ void k_detect(const unsigned short* __restrict__ x, int* __restrict__ flag) {
    __shared__ int cnt;
    if (threadIdx.x == 0) cnt = 0;
    __syncthreads();
    int sane = 0;
#pragma unroll
    for (int j = 0; j < 16; ++j) {
        unsigned short u = x[threadIdx.x * 16 + j];
        int e = (u >> 7) & 0xFF;
        if (e > 0x60 && e < 0xA0) sane++;
    }
    atomicAdd(&cnt, sane);
    __syncthreads();
    if (threadIdx.x == 0) *flag = (cnt > 3686) ? 1 : 0;
}

// ---------- weight conversion: (bf16|f32) -> f32 scratch ----------
struct CvtDesc { const void* src[22]; int n[22]; int off[22]; };

__global__ void k_cvt(CvtDesc d, float* __restrict__ wts, const int* __restrict__ flag) {
    int t = blockIdx.y;
    int n = d.n[t];
    bool isbf = (*flag != 0);
    const unsigned short* sb = (const unsigned short*)d.src[t];
    const float* sf = (const float*)d.src[t];
    float* o = wts + d.off[t];
    for (int i = blockIdx.x * blockDim.x + threadIdx.x; i < n; i += gridDim.x * blockDim.x)
        o[i] = isbf ? bf2f(sb[i]) : sf[i];
}

// ---------- pack SAGE weights into MFMA fragment order, bf16 hi/lo ----------
// W_L = [Wl_L (128x128) ; Wr_L (128x128)]  (256 x 128, k-major)
__global__ void k_packW(const float* __restrict__ wts, int4 oWl, int4 oWr,
                        unsigned short* __restrict__ Wpack) {
    int idx = blockIdx.x * 256 + threadIdx.x;
    if (idx >= 4 * 8 * 8 * 64 * 8) return;
    int L    = idx >> 15;
    int rem  = idx & 32767;
    int ct   = rem >> 12;
    int rem2 = rem & 4095;
    int ks   = rem2 >> 9;
    int rem3 = rem2 & 511;
    int lane = rem3 >> 3;
    int j    = rem3 & 7;
    int k   = ks * 32 + (lane >> 4) * 8 + j;
    int col = ct * 16 + (lane & 15);
    int ol = (L == 0) ? oWl.x : (L == 1) ? oWl.y : (L == 2) ? oWl.z : oWl.w;
    int orr = (L == 0) ? oWr.x : (L == 1) ? oWr.y : (L == 2) ? oWr.z : oWr.w;
    float w = (k < 128) ? wts[ol + k * 128 + col] : wts[orr + (k - 128) * 128 + col];
    unsigned short hi = f2bf(w);
    unsigned short lo = f2bf(w - bf2f(hi));
    int base = L * 65536 + (ct * 8 + ks) * 512 + lane * 8 + j;
    Wpack[base]         = hi;
    Wpack[base + 32768] = lo;
}

// ---------- load x -> f32 ----------
__global__ void k_load_x(const void* __restrict__ x, float* __restrict__ out,
                         const int* __restrict__ flag, int n4) {
    int i = blockIdx.x * blockDim.x + threadIdx.x;
    if (i >= n4) return;
    if (*flag) {
        ushort4 v = ((const ushort4*)x)[i];
        float4 o;
        o.x = bf2f(v.x); o.y = bf2f(v.y); o.z = bf2f(v.z); o.w = bf2f(v.w);
        ((float4*)out)[i] = o;
    } else {
        ((float4*)out)[i] = ((const float4*)x)[i];
    }
}

__global__ void k_init_nm(float* __restrict__ nm) {
    int i = blockIdx.x * blockDim.x + threadIdx.x;
    if (i < NT) nm[i] = 1.0f;
}

// ---------- CSR build (by dst) ----------
__global__ void k_hist(const int* __restrict__ dst, int* __restrict__ cnt) {
    int e = blockIdx.x * blockDim.x + threadIdx.x;
    if (e < NE) atomicAdd(&cnt[dst[e]], 1);
}

__global__ void k_scan1(const int* __restrict__ cnt, int* __restrict__ rp, int* __restrict__ bsum) {
    __shared__ int s[256];
    int t = threadIdx.x;
    int i = blockIdx.x * 256 + t;
    int v = cnt[i];
    s[t] = v;
    __syncthreads();
    for (int off = 1; off < 256; off <<= 1) {
        int a = (t >= off) ? s[t - off] : 0;
        __syncthreads();
        s[t] += a;
        __syncthreads();
    }
    rp[i] = s[t] - v;
    if (t == 255) bsum[blockIdx.x] = s[255];
}

__global__ void k_scan2(const int* __restrict__ bsum, int* __restrict__ boff) {
    __shared__ int s[256];
    int t = threadIdx.x;
    int v = bsum[t];
    s[t] = v;
    __syncthreads();
    for (int off = 1; off < 256; off <<= 1) {
        int a = (t >= off) ? s[t - off] : 0;
        __syncthreads();
        s[t] += a;
        __syncthreads();
    }
    boff[t] = s[t] - v;
}

__global__ void k_scan3(int* __restrict__ rp, const int* __restrict__ boff) {
    int i = blockIdx.x * 256 + threadIdx.x;
    rp[i] += boff[i >> 8];
    if (i == 0) rp[NT] = NE;
}

__global__ void k_scatter(const int* __restrict__ src, const int* __restrict__ dst,
                          const int* __restrict__ rp, int* __restrict__ fill, int* __restrict__ col) {
    int e = blockIdx.x * blockDim.x + threadIdx.x;
    if (e < NE) {
        int d = dst[e];
        int p = rp[d] + atomicAdd(&fill[d], 1);
        col[p] = src[e];
    }
}

// ---------- fused SAGE layer: gather-mean -> LDS -> MFMA dual-GEMM ----------
// out = relu([mean_j h[j]*ts[j] | h*ts] @ [Wl;Wr] + bl) * nm
// split-bf16: A ~ Ahi + Alo; C = Ahi*Whi + Alo*Whi + Ahi*Wlo
__device__ __forceinline__ int lds_sw(int node, int k) {
    // [64][128] ushort row-major, 16B-granule XOR swizzle
    int g = k >> 3;
    int go = g ^ (node & 7);
    return node * 128 + go * 8 + (k & 7);
}

__global__ void __launch_bounds__(256) k_sage_fused(
    const float* __restrict__ h, const float* __restrict__ ts,   // ts == nullptr -> 1.0
    const float* __restrict__ nm,
    const int* __restrict__ rp, const int* __restrict__ col,
    const unsigned short* __restrict__ Wp, const float* __restrict__ bl,
    float* __restrict__ out)
{
    __shared__ unsigned short Ahi[64 * 128];
    __shared__ unsigned short Alo[64 * 128];
    int tid = threadIdx.x;
    int b = blockIdx.x;
    // XCD-aware: consecutive-XCD blocks (b&7) share 4 graphs -> 4MB L2 working set
    int graph = (b & 7) * 4 + ((b >> 3) >> 5);
    int tile  = (b >> 3) & 31;
    int n0 = graph * NPGC + tile * 64;

    int lane = tid & 63, w = tid >> 6;
    int lrow = lane & 15, quad = lane >> 4;
    f32x4 acc[4][2] = {};

    // ---- phase A: gather mean rows (K 0..127) ----
#pragma unroll 2
    for (int pass = 0; pass < 8; ++pass) {
        int node = pass * 8 + (tid >> 5);
        int f = (tid & 31) * 4;
        int gn = n0 + node;
        int beg = rp[gn], end = rp[gn + 1];
        float ax = 0.f, ay = 0.f, az = 0.f, aw = 0.f, cnt = 0.f;
        for (int e = beg; e < end; ++e) {
            int s = col[e];
            float4 v = *(const float4*)&h[(size_t)s * HID + f];
            float sc = ts ? ts[s] : 1.0f;
            ax += v.x * sc; ay += v.y * sc; az += v.z * sc; aw += v.w * sc;
            cnt += nm[s];
        }
        float inv = 1.0f / fmaxf(cnt, 1.0f);
        float m0 = ax * inv, m1 = ay * inv, m2 = az * inv, m3 = aw * inv;
        ushort4 hi4, lo4;
        hi4.x = f2bf(m0); lo4.x = f2bf(m0 - bf2f(hi4.x));
        hi4.y = f2bf(m1); lo4.y = f2bf(m1 - bf2f(hi4.y));
        hi4.z = f2bf(m2); lo4.z = f2bf(m2 - bf2f(hi4.z));
        hi4.w = f2bf(m3); lo4.w = f2bf(m3 - bf2f(hi4.w));
        int a = lds_sw(node, f);
        *(ushort4*)&Ahi[a] = hi4;
        *(ushort4*)&Alo[a] = lo4;
    }
    __syncthreads();

    // ---- MFMA over Wl half (ks 0..3) ----
#pragma unroll
    for (int ks = 0; ks < 4; ++ks) {
        short8 bh[2], blo[2];
#pragma unroll
        for (int c = 0; c < 2; ++c) {
            int ct = 2 * w + c;
            bh[c]  = *(const short8*)&Wp[(ct * 8 + ks) * 512 + lane * 8];
            blo[c] = *(const short8*)&Wp[32768 + (ct * 8 + ks) * 512 + lane * 8];
        }
        int kb = ks * 32 + quad * 8;
#pragma unroll
        for (int st = 0; st < 4; ++st) {
            int a = lds_sw(st * 16 + lrow, kb);
            short8 ah = *(const short8*)&Ahi[a];
            short8 al = *(const short8*)&Alo[a];
#pragma unroll
            for (int c = 0; c < 2; ++c) {
                acc[st][c] = __builtin_amdgcn_mfma_f32_16x16x32_bf16(ah, bh[c],  acc[st][c], 0, 0, 0);
                acc[st][c] = __builtin_amdgcn_mfma_f32_16x16x32_bf16(al, bh[c],  acc[st][c], 0, 0, 0);
                acc[st][c] = __builtin_amdgcn_mfma_f32_16x16x32_bf16(ah, blo[c], acc[st][c], 0, 0, 0);
            }
        }
    }
    __syncthreads();

    // ---- phase B: stage root h rows (K 128..255 -> local 0..127) ----
#pragma unroll
    for (int i = 0; i < 8; ++i) {
        int idx = i * 256 + tid;
        int node = idx >> 5;
        int f = (idx & 31) * 4;
        int gn = n0 + node;
        float4 v = *(const float4*)&h[(size_t)gn * HID + f];
        float sc = ts ? ts[gn] : 1.0f;
        float v0 = v.x * sc, v1 = v.y * sc, v2 = v.z * sc, v3 = v.w * sc;
        ushort4 hi4, lo4;
        hi4.x = f2bf(v0); lo4.x = f2bf(v0 - bf2f(hi4.x));
        hi4.y = f2bf(v1); lo4.y = f2bf(v1 - bf2f(hi4.y));
        hi4.z = f2bf(v2); lo4.z = f2bf(v2 - bf2f(hi4.z));
        hi4.w = f2bf(v3); lo4.w = f2bf(v3 - bf2f(hi4.w));
        int a = lds_sw(node, f);
        *(ushort4*)&Ahi[a] = hi4;
        *(ushort4*)&Alo[a] = lo4;
    }
    __syncthreads();

    // ---- MFMA over Wr half (ks 4..7) ----
#pragma unroll
    for (int ks = 4; ks < 8; ++ks) {
        short8 bh[2], blo[2];
#pragma unroll
        for (int c = 0; c < 2; ++c) {
            int ct = 2 * w + c;
            bh[c]  = *(const short8*)&Wp[(ct * 8 + ks) * 512 + lane * 8];
            blo[c] = *(const short8*)&Wp[32768 + (ct * 8 + ks) * 512 + lane * 8];
        }
        int kb = (ks - 4) * 32 + quad * 8;
#pragma unroll
        for (int st = 0; st < 4; ++st) {
            int a = lds_sw(st * 16 + lrow, kb);
            short8 ah = *(const short8*)&Ahi[a];
            short8 al = *(const short8*)&Alo[a];
#pragma unroll
            for (int c = 0; c < 2; ++c) {
                acc[st][c] = __builtin_amdgcn_mfma_f32_16x16x32_bf16(ah, bh[c],  acc[st][c], 0, 0, 0);
                acc[st][c] = __builtin_amdgcn_mfma_f32_16x16x32_bf16(al, bh[c],  acc[st][c], 0, 0, 0);
                acc[st][c] = __builtin_amdgcn_mfma_f32_16x16x32_bf16(ah, blo[c], acc[st][c], 0, 0, 0);
            }
        }
    }

    // ---- epilogue: C/D layout col=lane&15, row=quad*4+reg ----
#pragma unroll
    for (int c = 0; c < 2; ++c) {
        int colg = (2 * w + c) * 16 + lrow;
        float bias = bl[colg];
#pragma unroll
        for (int st = 0; st < 4; ++st) {
#pragma unroll
            for (int r = 0; r < 4; ++r) {
                int node = n0 + st * 16 + quad * 4 + r;
                float val = fmaxf(acc[st][c][r] + bias, 0.f) * nm[node];
                out[(size_t)node * HID + colg] = val;
            }
        }
    }
}

// ---------- per-node dots with Prel / Proot ----------
__global__ void k_node_dots(const float* __restrict__ h, const float* __restrict__ Prel,
                            const float* __restrict__ Proot,
                            float* __restrict__ q, float* __restrict__ r) {
    int lane = threadIdx.x & 63;
    int node = blockIdx.x * 4 + (threadIdx.x >> 6);
    float h0 = h[node * HID + lane];
    float h1 = h[node * HID + 64 + lane];
    float qv = h0 * Prel[lane] + h1 * Prel[64 + lane];
    float rv = h0 * Proot[lane] + h1 * Proot[64 + lane];
    for (int o = 32; o > 0; o >>= 1) {
        qv += __shfl_down(qv, o, 64);
        rv += __shfl_down(rv, o, 64);
    }
    if (lane == 0) { q[node] = qv; r[node] = rv; }
}

// ---------- score = segsum(q[src]) + r + prb ----------
__global__ void k_score(const float* __restrict__ q, const float* __restrict__ r,
                        const float* __restrict__ prb,
                        const int* __restrict__ rp, const int* __restrict__ col,
                        float* __restrict__ score) {
    int n = blockIdx.x * 256 + threadIdx.x;
    int beg = rp[n], end = rp[n + 1];
    float s = 0.f;
    for (int e = beg; e < end; ++e) s += q[col[e]];
    score[n] = s + r[n] + prb[0];
}

// ---------- per-graph top-k; writes nm and t = tanh(score)*newm ----------
__global__ void __launch_bounds__(1024) k_topk(const float* __restrict__ score,
                                               float* __restrict__ nm,
                                               float* __restrict__ t, int k) {
    __shared__ unsigned long long keys[NPGC];
    __shared__ unsigned char msk[NPGC];
    int tid = threadIdx.x;
    int base = blockIdx.x * NPGC;
    for (int j = tid; j < NPGC; j += 1024) {
        float sc = (nm[base + j] > 0.f) ? score[base + j] : -1e30f;
        unsigned int u = __float_as_uint(sc);
        u = (u & 0x80000000u) ? ~u : (u | 0x80000000u);
        keys[j] = ((unsigned long long)u << 32) | (unsigned long long)(NPGC - 1 - j);
        msk[j] = 0;
    }
    for (int size = 2; size <= NPGC; size <<= 1) {
        for (int stride = size >> 1; stride > 0; stride >>= 1) {
            __syncthreads();
            for (int tt = tid; tt < NPGC; tt += 1024) {
                int partner = tt ^ stride;
                if (partner > tt) {
                    bool desc = ((tt & size) == 0);
                    unsigned long long a = keys[tt], b = keys[partner];
                    if ((a < b) == desc) { keys[tt] = b; keys[partner] = a; }
                }
            }
        }
    }
    __syncthreads();
    for (int j = tid; j < NPGC; j += 1024) {
        if (j < k) {
            int idx = NPGC - 1 - (int)(keys[j] & 0xFFFFFFFFull);
            msk[idx] = 1;
        }
    }
    __syncthreads();
    for (int j = tid; j < NPGC; j += 1024) {
        bool keep = msk[j] != 0;
        nm[base + j] = keep ? 1.0f : 0.0f;
        t[base + j]  = keep ? tanhf(score[base + j]) : 0.0f;
    }
}

// ---------- per-graph mean of h*t ----------
__global__ void k_gsum(const float* __restrict__ h, const float* __restrict__ t,
                       const float* __restrict__ nm,
                       float* __restrict__ g, float* __restrict__ gcnt) {
    int b = blockIdx.x;
    int graph = b >> 3, part = b & 7;
    int f = threadIdx.x & 127, sub = threadIdx.x >> 7;
    int nbase = graph * NPGC + part * 256 + sub * 128;
    float acc = 0.f, cnt = 0.f;
    for (int n = 0; n < 128; ++n) {
        acc += h[(size_t)(nbase + n) * HID + f] * t[nbase + n];
        cnt += nm[nbase + n];
    }
    atomicAdd(&g[graph * HID + f], acc);
    if (f == 0) atomicAdd(&gcnt[graph], cnt);
}

__global__ void k_gdiv(float* __restrict__ g, const float* __restrict__ gcnt) {
    int i = blockIdx.x * 256 + threadIdx.x;
    if (i < NG * HID) g[i] /= fmaxf(gcnt[i >> 7], 1.0f);
}

// ---------- MLP head + log_softmax ----------
__global__ void k_mlp(const float* __restrict__ g, const float* __restrict__ W5,
                      const float* __restrict__ b5, const float* __restrict__ W6,
                      const float* __restrict__ b6, void* __restrict__ out,
                      const int* __restrict__ flag) {
    __shared__ float g5[64];
    __shared__ float ls[2];
    int graph = blockIdx.x, j = threadIdx.x;
    float acc = b5[j];
    for (int f = 0; f < HID; ++f)
        acc += g[graph * HID + f] * W5[f * 64 + j];
    g5[j] = fmaxf(acc, 0.f);
    __syncthreads();
    if (j < 2) {
        float l = b6[j];
        for (int t = 0; t < 64; ++t) l += g5[t] * W6[t * 2 + j];
        ls[j] = l;
    }
    __syncthreads();
    if (j == 0) {
        float a = ls[0], b = ls[1];
        float mx = fmaxf(a, b);
        float lse = mx + logf(expf(a - mx) + expf(b - mx));
        if (*flag) {
            ((unsigned short*)out)[graph * 2 + 0] = f2bf(a - lse);
            ((unsigned short*)out)[graph * 2 + 1] = f2bf(b - lse);
        } else {
            ((float*)out)[graph * 2 + 0] = a - lse;
            ((float*)out)[graph * 2 + 1] = b - lse;
        }
    }
}

extern "C" void kernel_launch(void* const* d_in, const int* in_sizes, int n_in,
                              void* d_out, int out_size, void* d_ws, size_t ws_size,
                              hipStream_t stream) {
    const void* x    = d_in[0];
    const int*  ei   = (const int*)d_in[1];
    const int*  srcE = ei;
    const int*  dstE = ei + NE;

    char* ws = (char*)d_ws;
    float* hA    = (float*)(ws + 0);
    float* hB    = (float*)(ws + 33554432);
    float* tvec  = (float*)(ws + 67108864);        // 256 KB
    float* q     = (float*)(ws + 100663296);
    float* r     = (float*)(ws + 100925440);
    float* score = (float*)(ws + 101187584);
    float* nm    = (float*)(ws + 101449728);
    int*   rowc  = (int*)  (ws + 101711872);
    int*   rp    = (int*)  (ws + 101974016);
    int*   bsum  = (int*)  (ws + 102236416);
    int*   boff  = (int*)  (ws + 102237440);
    int*   fill  = (int*)  (ws + 102238464);
    int*   col   = (int*)  (ws + 102500608);
    float* g     = (float*)(ws + 104597760);
    float* gcnt  = (float*)(ws + 104614144);
    int*   flag  = (int*)  (ws + 104615936);
    float* wts   = (float*)(ws + 104616960);
    unsigned short* Wpack = (unsigned short*)(ws + 105179136);  // 512 KB
    (void)in_sizes; (void)n_in; (void)out_size; (void)ws_size;

    const int O_Wl1 = 0,      O_bl1 = 16384,  O_Wr1 = 16512;
    const int O_Wl2 = 32896,  O_bl2 = 49280,  O_Wr2 = 49408;
    const int O_Wl3 = 65792,  O_bl3 = 82176,  O_Wr3 = 82304;
    const int O_Wl4 = 98688,  O_bl4 = 115072, O_Wr4 = 115200;
    const int O_Pr1 = 131584, O_pb1 = 131712, O_Po1 = 131713;
    const int O_Pr2 = 131841, O_pb2 = 131969, O_Po2 = 131970;
    const int O_W5  = 132098, O_b5  = 140290, O_W6 = 140354, O_b6 = 140482;

    CvtDesc d;
    const int srcIdx[22] = {4,5,6,7,8,9,10,11,12,13,14,15,16,17,18,19,20,21,22,23,24,25};
    const int nelems[22] = {16384,128,16384, 16384,128,16384, 16384,128,16384, 16384,128,16384,
                            128,1,128, 128,1,128, 8192,64,128,2};
    const int offs[22]   = {O_Wl1,O_bl1,O_Wr1, O_Wl2,O_bl2,O_Wr2, O_Wl3,O_bl3,O_Wr3, O_Wl4,O_bl4,O_Wr4,
                            O_Pr1,O_pb1,O_Po1, O_Pr2,O_pb2,O_Po2, O_W5,O_b5,O_W6,O_b6};
    for (int i = 0; i < 22; ++i) { d.src[i] = d_in[srcIdx[i]]; d.n[i] = nelems[i]; d.off[i] = offs[i]; }

    hipMemsetAsync(rowc, 0, NT * 4, stream);
    hipMemsetAsync(fill, 0, NT * 4, stream);
    hipMemsetAsync(g, 0, (NG * HID + NG + 512) * 4, stream);

    k_detect <<<1, 256, 0, stream>>>((const unsigned short*)x, flag);
    k_cvt    <<<dim3(64, 22), 256, 0, stream>>>(d, wts, flag);
    k_packW  <<<512, 256, 0, stream>>>(wts, make_int4(O_Wl1, O_Wl2, O_Wl3, O_Wl4),
                                       make_int4(O_Wr1, O_Wr2, O_Wr3, O_Wr4), Wpack);
    k_load_x <<<8192, 256, 0, stream>>>(x, hA, flag, NT * HID / 4);
    k_init_nm<<<256, 256, 0, stream>>>(nm);

    k_hist   <<<2048, 256, 0, stream>>>(dstE, rowc);
    k_scan1  <<<256, 256, 0, stream>>>(rowc, rp, bsum);
    k_scan2  <<<1, 256, 0, stream>>>(bsum, boff);
    k_scan3  <<<256, 256, 0, stream>>>(rp, boff);
    k_scatter<<<2048, 256, 0, stream>>>(srcE, dstE, rp, fill, col);

    // layer 1: hA -> hB
    k_sage_fused<<<1024, 256, 0, stream>>>(hA, nullptr, nm, rp, col, Wpack + 0 * 65536, wts + O_bl1, hB);
    // layer 2: hB -> hA
    k_sage_fused<<<1024, 256, 0, stream>>>(hB, nullptr, nm, rp, col, Wpack + 1 * 65536, wts + O_bl2, hA);

    // pool 1 (k = 1024)
    k_node_dots<<<16384, 256, 0, stream>>>(hA, wts + O_Pr1, wts + O_Po1, q, r);
    k_score    <<<256, 256, 0, stream>>>(q, r, wts + O_pb1, rp, col, score);
    k_topk     <<<32, 1024, 0, stream>>>(score, nm, tvec, 1024);

    // layer 3: hA (scaled by tvec on the fly) -> hB
    k_sage_fused<<<1024, 256, 0, stream>>>(hA, tvec, nm, rp, col, Wpack + 2 * 65536, wts + O_bl3, hB);
    // layer 4: hB -> hA
    k_sage_fused<<<1024, 256, 0, stream>>>(hB, nullptr, nm, rp, col, Wpack + 3 * 65536, wts + O_bl4, hA);

    // pool 2 (k = 512)
    k_node_dots<<<16384, 256, 0, stream>>>(hA, wts + O_Pr2, wts + O_Po2, q, r);
    k_score    <<<256, 256, 0, stream>>>(q, r, wts + O_pb2, rp, col, score);
    k_topk     <<<32, 1024, 0, stream>>>(score, nm, tvec, 512);

    // readout (h*t folded in)
    k_gsum<<<256, 256, 0, stream>>>(hA, tvec, nm, g, gcnt);
    k_gdiv<<<16, 256, 0, stream>>>(g, gcnt);
    k_mlp <<<32, 64, 0, stream>>>(g, wts + O_W5, wts + O_b5, wts + O_W6, wts + O_b6, d_out, flag);
}

// Round 5
// 483.117 us; speedup vs baseline: 2.0426x; 1.1049x over previous
//
#include <hip/hip_runtime.h>
#include <hip/hip_bf16.h>
#include <math.h>

#define NT   65536      // total nodes (32 graphs * 2048)
#define NPGC 2048       // nodes per graph
#define NG   32         // graphs
#define NE   524288     // edges
#define HID  128

typedef short short8 __attribute__((ext_vector_type(8)));
typedef float f32x4  __attribute__((ext_vector_type(4)));

__device__ __forceinline__ float bf2f(unsigned short u) {
    union { unsigned int i; float f; } v; v.i = ((unsigned int)u) << 16; return v.f;
}
__device__ __forceinline__ unsigned short f2bf(float f) {
    union { float f; unsigned int i; } v; v.f = f;
    unsigned int x = v.i;
    return (unsigned short)((x + 0x7fffu + ((x >> 16) & 1u)) >> 16);
}

// ---------- dtype detection: bf16 vs fp32 ----------
__global__ void k_detect(const unsigned short* __restrict__ x, int* __restrict__ flag) {
    __shared__ int cnt;
    if (threadIdx.x == 0) cnt = 0;
    __syncthreads();
    int sane = 0;
#pragma unroll
    for (int j = 0; j < 16; ++j) {
        unsigned short u = x[threadIdx.x * 16 + j];
        int e = (u >> 7) & 0xFF;
        if (e > 0x60 && e < 0xA0) sane++;
    }
    atomicAdd(&cnt, sane);
    __syncthreads();
    if (threadIdx.x == 0) *flag = (cnt > 3686) ? 1 : 0;
}

// ---------- weight conversion: (bf16|f32) -> f32 scratch ----------
struct CvtDesc { const void* src[22]; int n[22]; int off[22]; };

__global__ void k_cvt(CvtDesc d, float* __restrict__ wts, const int* __restrict__ flag) {
    int t = blockIdx.y;
    int n = d.n[t];
    bool isbf = (*flag != 0);
    const unsigned short* sb = (const unsigned short*)d.src[t];
    const float* sf = (const float*)d.src[t];
    float* o = wts + d.off[t];
    for (int i = blockIdx.x * blockDim.x + threadIdx.x; i < n; i += gridDim.x * blockDim.x)
        o[i] = isbf ? bf2f(sb[i]) : sf[i];
}

// ---------- pack SAGE weights into MFMA fragment order, bf16 hi/lo ----------
// W_L = [Wl_L (128x128) ; Wr_L (128x128)]  (256 x 128, k-major)
__global__ void k_packW(const float* __restrict__ wts, int4 oWl, int4 oWr,
                        unsigned short* __restrict__ Wpack) {
    int idx = blockIdx.x * 256 + threadIdx.x;
    if (idx >= 4 * 8 * 8 * 64 * 8) return;
    int L    = idx >> 15;
    int rem  = idx & 32767;
    int ct   = rem >> 12;
    int rem2 = rem & 4095;
    int ks   = rem2 >> 9;
    int rem3 = rem2 & 511;
    int lane = rem3 >> 3;
    int j    = rem3 & 7;
    int k   = ks * 32 + (lane >> 4) * 8 + j;
    int col = ct * 16 + (lane & 15);
    int ol = (L == 0) ? oWl.x : (L == 1) ? oWl.y : (L == 2) ? oWl.z : oWl.w;
    int orr = (L == 0) ? oWr.x : (L == 1) ? oWr.y : (L == 2) ? oWr.z : oWr.w;
    float w = (k < 128) ? wts[ol + k * 128 + col] : wts[orr + (k - 128) * 128 + col];
    unsigned short hi = f2bf(w);
    unsigned short lo = f2bf(w - bf2f(hi));
    int base = L * 65536 + (ct * 8 + ks) * 512 + lane * 8 + j;
    Wpack[base]         = hi;
    Wpack[base + 32768] = lo;
}

// ---------- load x -> f32 ----------
__global__ void k_load_x(const void* __restrict__ x, float* __restrict__ out,
                         const int* __restrict__ flag, int n4) {
    int i = blockIdx.x * blockDim.x + threadIdx.x;
    if (i >= n4) return;
    if (*flag) {
        ushort4 v = ((const ushort4*)x)[i];
        float4 o;
        o.x = bf2f(v.x); o.y = bf2f(v.y); o.z = bf2f(v.z); o.w = bf2f(v.w);
        ((float4*)out)[i] = o;
    } else {
        ((float4*)out)[i] = ((const float4*)x)[i];
    }
}

__global__ void k_init_nm(float* __restrict__ nm) {
    int i = blockIdx.x * blockDim.x + threadIdx.x;
    if (i < NT) nm[i] = 1.0f;
}

// ---------- CSR build (by dst) ----------
__global__ void k_hist(const int* __restrict__ dst, int* __restrict__ cnt) {
    int e = blockIdx.x * blockDim.x + threadIdx.x;
    if (e < NE) atomicAdd(&cnt[dst[e]], 1);
}

__global__ void k_scan1(const int* __restrict__ cnt, int* __restrict__ rp, int* __restrict__ bsum) {
    __shared__ int s[256];
    int t = threadIdx.x;
    int i = blockIdx.x * 256 + t;
    int v = cnt[i];
    s[t] = v;
    __syncthreads();
    for (int off = 1; off < 256; off <<= 1) {
        int a = (t >= off) ? s[t - off] : 0;
        __syncthreads();
        s[t] += a;
        __syncthreads();
    }
    rp[i] = s[t] - v;
    if (t == 255) bsum[blockIdx.x] = s[255];
}

__global__ void k_scan2(const int* __restrict__ bsum, int* __restrict__ boff) {
    __shared__ int s[256];
    int t = threadIdx.x;
    int v = bsum[t];
    s[t] = v;
    __syncthreads();
    for (int off = 1; off < 256; off <<= 1) {
        int a = (t >= off) ? s[t - off] : 0;
        __syncthreads();
        s[t] += a;
        __syncthreads();
    }
    boff[t] = s[t] - v;
}

__global__ void k_scan3(int* __restrict__ rp, const int* __restrict__ boff) {
    int i = blockIdx.x * 256 + threadIdx.x;
    rp[i] += boff[i >> 8];
    if (i == 0) rp[NT] = NE;
}

__global__ void k_scatter(const int* __restrict__ src, const int* __restrict__ dst,
                          const int* __restrict__ rp, int* __restrict__ fill, int* __restrict__ col) {
    int e = blockIdx.x * blockDim.x + threadIdx.x;
    if (e < NE) {
        int d = dst[e];
        int p = rp[d] + atomicAdd(&fill[d], 1);
        col[p] = src[e];
    }
}

// ---------- invc[n] = 1 / max(sum_in nm[col], 1) ----------
__global__ void k_invc(const float* __restrict__ nm, const int* __restrict__ rp,
                       const int* __restrict__ col, float* __restrict__ invc) {
    int n = blockIdx.x * 256 + threadIdx.x;
    int beg = rp[n], end = rp[n + 1];
    float c = 0.f;
    for (int e = beg; e < end; ++e) c += nm[col[e]];
    invc[n] = 1.0f / fmaxf(c, 1.0f);
}

// ---------- fused SAGE layer: gather-mean -> LDS -> MFMA dual-GEMM ----------
// out = relu([mean_j h[j]*ts[j] | h*ts] @ [Wl;Wr] + bl) * nm
// split-bf16: A ~ Ahi + Alo; C = Ahi*Whi + Alo*Whi + Ahi*Wlo
__device__ __forceinline__ int lds_sw(int node, int k) {
    // [32][128] ushort row-major, 16B-granule XOR swizzle
    int g = k >> 3;
    int go = g ^ (node & 7);
    return node * 128 + go * 8 + (k & 7);
}

__global__ void __launch_bounds__(256, 8) k_sage_fused(
    const float* __restrict__ h, const float* __restrict__ ts,   // ts == nullptr -> 1.0
    const float* __restrict__ nm, const float* __restrict__ invc,
    const int* __restrict__ rp, const int* __restrict__ col,
    const unsigned short* __restrict__ Wp, const float* __restrict__ bl,
    float* __restrict__ out)
{
    __shared__ unsigned short Ahi[32 * 128];
    __shared__ unsigned short Alo[32 * 128];
    int tid = threadIdx.x;
    int b = blockIdx.x;
    // XCD-aware: blocks with same (b&7) land on one XCD; give each XCD 4 graphs
    int graph = (b & 7) * 4 + ((b >> 3) >> 6);
    int tile  = (b >> 3) & 63;                 // 64 tiles of 32 nodes per graph
    int n0 = graph * NPGC + tile * 32;

    int lane = tid & 63, w = tid >> 6;
    int lrow = lane & 15, quad = lane >> 4;
    f32x4 acc[2][2] = {};

    // ---- phase A: gather mean rows (K 0..127) ----
#pragma unroll
    for (int pass = 0; pass < 4; ++pass) {
        int node = pass * 8 + (tid >> 5);
        int f = (tid & 31) * 4;
        int gn = n0 + node;
        int beg = rp[gn], end = rp[gn + 1];
        float ax = 0.f, ay = 0.f, az = 0.f, aw = 0.f;
        for (int e = beg; e < end; ++e) {
            int s = col[e];
            float4 v = *(const float4*)&h[(size_t)s * HID + f];
            float sc = ts ? ts[s] : 1.0f;
            ax += v.x * sc; ay += v.y * sc; az += v.z * sc; aw += v.w * sc;
        }
        float inv = invc[gn];
        float m0 = ax * inv, m1 = ay * inv, m2 = az * inv, m3 = aw * inv;
        ushort4 hi4, lo4;
        hi4.x = f2bf(m0); lo4.x = f2bf(m0 - bf2f(hi4.x));
        hi4.y = f2bf(m1); lo4.y = f2bf(m1 - bf2f(hi4.y));
        hi4.z = f2bf(m2); lo4.z = f2bf(m2 - bf2f(hi4.z));
        hi4.w = f2bf(m3); lo4.w = f2bf(m3 - bf2f(hi4.w));
        int a = lds_sw(node, f);
        *(ushort4*)&Ahi[a] = hi4;
        *(ushort4*)&Alo[a] = lo4;
    }
    __syncthreads();

    // ---- MFMA over Wl half (ks 0..3) ----
#pragma unroll
    for (int ks = 0; ks < 4; ++ks) {
        short8 bh[2], blo[2];
#pragma unroll
        for (int c = 0; c < 2; ++c) {
            int ct = 2 * w + c;
            bh[c]  = *(const short8*)&Wp[(ct * 8 + ks) * 512 + lane * 8];
            blo[c] = *(const short8*)&Wp[32768 + (ct * 8 + ks) * 512 + lane * 8];
        }
        int kb = ks * 32 + quad * 8;
#pragma unroll
        for (int st = 0; st < 2; ++st) {
            int a = lds_sw(st * 16 + lrow, kb);
            short8 ah = *(const short8*)&Ahi[a];
            short8 al = *(const short8*)&Alo[a];
#pragma unroll
            for (int c = 0; c < 2; ++c) {
                acc[st][c] = __builtin_amdgcn_mfma_f32_16x16x32_bf16(ah, bh[c],  acc[st][c], 0, 0, 0);
                acc[st][c] = __builtin_amdgcn_mfma_f32_16x16x32_bf16(al, bh[c],  acc[st][c], 0, 0, 0);
                acc[st][c] = __builtin_amdgcn_mfma_f32_16x16x32_bf16(ah, blo[c], acc[st][c], 0, 0, 0);
            }
        }
    }
    __syncthreads();

    // ---- phase B: stage root h rows (K 128..255 -> local 0..127) ----
#pragma unroll
    for (int i = 0; i < 4; ++i) {
        int idx = i * 256 + tid;
        int node = idx >> 5;
        int f = (idx & 31) * 4;
        int gn = n0 + node;
        float4 v = *(const float4*)&h[(size_t)gn * HID + f];
        float sc = ts ? ts[gn] : 1.0f;
        float v0 = v.x * sc, v1 = v.y * sc, v2 = v.z * sc, v3 = v.w * sc;
        ushort4 hi4, lo4;
        hi4.x = f2bf(v0); lo4.x = f2bf(v0 - bf2f(hi4.x));
        hi4.y = f2bf(v1); lo4.y = f2bf(v1 - bf2f(hi4.y));
        hi4.z = f2bf(v2); lo4.z = f2bf(v2 - bf2f(hi4.z));
        hi4.w = f2bf(v3); lo4.w = f2bf(v3 - bf2f(hi4.w));
        int a = lds_sw(node, f);
        *(ushort4*)&Ahi[a] = hi4;
        *(ushort4*)&Alo[a] = lo4;
    }
    __syncthreads();

    // ---- MFMA over Wr half (ks 4..7) ----
#pragma unroll
    for (int ks = 4; ks < 8; ++ks) {
        short8 bh[2], blo[2];
#pragma unroll
        for (int c = 0; c < 2; ++c) {
            int ct = 2 * w + c;
            bh[c]  = *(const short8*)&Wp[(ct * 8 + ks) * 512 + lane * 8];
            blo[c] = *(const short8*)&Wp[32768 + (ct * 8 + ks) * 512 + lane * 8];
        }
        int kb = (ks - 4) * 32 + quad * 8;
#pragma unroll
        for (int st = 0; st < 2; ++st) {
            int a = lds_sw(st * 16 + lrow, kb);
            short8 ah = *(const short8*)&Ahi[a];
            short8 al = *(const short8*)&Alo[a];
#pragma unroll
            for (int c = 0; c < 2; ++c) {
                acc[st][c] = __builtin_amdgcn_mfma_f32_16x16x32_bf16(ah, bh[c],  acc[st][c], 0, 0, 0);
                acc[st][c] = __builtin_amdgcn_mfma_f32_16x16x32_bf16(al, bh[c],  acc[st][c], 0, 0, 0);
                acc[st][c] = __builtin_amdgcn_mfma_f32_16x16x32_bf16(ah, blo[c], acc[st][c], 0, 0, 0);
            }
        }
    }

    // ---- epilogue: C/D layout col=lane&15, row=quad*4+reg ----
#pragma unroll
    for (int c = 0; c < 2; ++c) {
        int colg = (2 * w + c) * 16 + lrow;
        float bias = bl[colg];
#pragma unroll
        for (int st = 0; st < 2; ++st) {
#pragma unroll
            for (int r = 0; r < 4; ++r) {
                int node = n0 + st * 16 + quad * 4 + r;
                float val = fmaxf(acc[st][c][r] + bias, 0.f) * nm[node];
                out[(size_t)node * HID + colg] = val;
            }
        }
    }
}

// ---------- per-node dots with Prel / Proot ----------
__global__ void k_node_dots(const float* __restrict__ h, const float* __restrict__ Prel,
                            const float* __restrict__ Proot,
                            float* __restrict__ q, float* __restrict__ r) {
    int lane = threadIdx.x & 63;
    int node = blockIdx.x * 4 + (threadIdx.x >> 6);
    float h0 = h[node * HID + lane];
    float h1 = h[node * HID + 64 + lane];
    float qv = h0 * Prel[lane] + h1 * Prel[64 + lane];
    float rv = h0 * Proot[lane] + h1 * Proot[64 + lane];
    for (int o = 32; o > 0; o >>= 1) {
        qv += __shfl_down(qv, o, 64);
        rv += __shfl_down(rv, o, 64);
    }
    if (lane == 0) { q[node] = qv; r[node] = rv; }
}

// ---------- score = segsum(q[src]) + r + prb ----------
__global__ void k_score(const float* __restrict__ q, const float* __restrict__ r,
                        const float* __restrict__ prb,
                        const int* __restrict__ rp, const int* __restrict__ col,
                        float* __restrict__ score) {
    int n = blockIdx.x * 256 + threadIdx.x;
    int beg = rp[n], end = rp[n + 1];
    float s = 0.f;
    for (int e = beg; e < end; ++e) s += q[col[e]];
    score[n] = s + r[n] + prb[0];
}

// ---------- per-graph top-k; writes nm and t = tanh(score)*newm ----------
__global__ void __launch_bounds__(1024) k_topk(const float* __restrict__ score,
                                               float* __restrict__ nm,
                                               float* __restrict__ t, int k) {
    __shared__ unsigned long long keys[NPGC];
    __shared__ unsigned char msk[NPGC];
    int tid = threadIdx.x;
    int base = blockIdx.x * NPGC;
    for (int j = tid; j < NPGC; j += 1024) {
        float sc = (nm[base + j] > 0.f) ? score[base + j] : -1e30f;
        unsigned int u = __float_as_uint(sc);
        u = (u & 0x80000000u) ? ~u : (u | 0x80000000u);
        keys[j] = ((unsigned long long)u << 32) | (unsigned long long)(NPGC - 1 - j);
        msk[j] = 0;
    }
    for (int size = 2; size <= NPGC; size <<= 1) {
        for (int stride = size >> 1; stride > 0; stride >>= 1) {
            __syncthreads();
            for (int tt = tid; tt < NPGC; tt += 1024) {
                int partner = tt ^ stride;
                if (partner > tt) {
                    bool desc = ((tt & size) == 0);
                    unsigned long long a = keys[tt], b = keys[partner];
                    if ((a < b) == desc) { keys[tt] = b; keys[partner] = a; }
                }
            }
        }
    }
    __syncthreads();
    for (int j = tid; j < NPGC; j += 1024) {
        if (j < k) {
            int idx = NPGC - 1 - (int)(keys[j] & 0xFFFFFFFFull);
            msk[idx] = 1;
        }
    }
    __syncthreads();
    for (int j = tid; j < NPGC; j += 1024) {
        bool keep = msk[j] != 0;
        nm[base + j] = keep ? 1.0f : 0.0f;
        t[base + j]  = keep ? tanhf(score[base + j]) : 0.0f;
    }
}

// ---------- per-graph mean of h*t ----------
__global__ void k_gsum(const float* __restrict__ h, const float* __restrict__ t,
                       const float* __restrict__ nm,
                       float* __restrict__ g, float* __restrict__ gcnt) {
    int b = blockIdx.x;
    int graph = b >> 3, part = b & 7;
    int f = threadIdx.x & 127, sub = threadIdx.x >> 7;
    int nbase = graph * NPGC + part * 256 + sub * 128;
    float acc = 0.f, cnt = 0.f;
    for (int n = 0; n < 128; ++n) {
        acc += h[(size_t)(nbase + n) * HID + f] * t[nbase + n];
        cnt += nm[nbase + n];
    }
    atomicAdd(&g[graph * HID + f], acc);
    if (f == 0) atomicAdd(&gcnt[graph], cnt);
}

__global__ void k_gdiv(float* __restrict__ g, const float* __restrict__ gcnt) {
    int i = blockIdx.x * 256 + threadIdx.x;
    if (i < NG * HID) g[i] /= fmaxf(gcnt[i >> 7], 1.0f);
}

// ---------- MLP head + log_softmax ----------
__global__ void k_mlp(const float* __restrict__ g, const float* __restrict__ W5,
                      const float* __restrict__ b5, const float* __restrict__ W6,
                      const float* __restrict__ b6, void* __restrict__ out,
                      const int* __restrict__ flag) {
    __shared__ float g5[64];
    __shared__ float ls[2];
    int graph = blockIdx.x, j = threadIdx.x;
    float acc = b5[j];
    for (int f = 0; f < HID; ++f)
        acc += g[graph * HID + f] * W5[f * 64 + j];
    g5[j] = fmaxf(acc, 0.f);
    __syncthreads();
    if (j < 2) {
        float l = b6[j];
        for (int t = 0; t < 64; ++t) l += g5[t] * W6[t * 2 + j];
        ls[j] = l;
    }
    __syncthreads();
    if (j == 0) {
        float a = ls[0], b = ls[1];
        float mx = fmaxf(a, b);
        float lse = mx + logf(expf(a - mx) + expf(b - mx));
        if (*flag) {
            ((unsigned short*)out)[graph * 2 + 0] = f2bf(a - lse);
            ((unsigned short*)out)[graph * 2 + 1] = f2bf(b - lse);
        } else {
            ((float*)out)[graph * 2 + 0] = a - lse;
            ((float*)out)[graph * 2 + 1] = b - lse;
        }
    }
}

extern "C" void kernel_launch(void* const* d_in, const int* in_sizes, int n_in,
                              void* d_out, int out_size, void* d_ws, size_t ws_size,
                              hipStream_t stream) {
    const void* x    = d_in[0];
    const int*  ei   = (const int*)d_in[1];
    const int*  srcE = ei;
    const int*  dstE = ei + NE;

    char* ws = (char*)d_ws;
    float* hA    = (float*)(ws + 0);
    float* hB    = (float*)(ws + 33554432);
    float* tvec  = (float*)(ws + 67108864);        // 256 KB
    float* invc  = (float*)(ws + 67371008);        // 256 KB
    float* q     = (float*)(ws + 100663296);
    float* r     = (float*)(ws + 100925440);
    float* score = (float*)(ws + 101187584);
    float* nm    = (float*)(ws + 101449728);
    int*   rowc  = (int*)  (ws + 101711872);
    int*   rp    = (int*)  (ws + 101974016);
    int*   bsum  = (int*)  (ws + 102236416);
    int*   boff  = (int*)  (ws + 102237440);
    int*   fill  = (int*)  (ws + 102238464);
    int*   col   = (int*)  (ws + 102500608);
    float* g     = (float*)(ws + 104597760);
    float* gcnt  = (float*)(ws + 104614144);
    int*   flag  = (int*)  (ws + 104615936);
    float* wts   = (float*)(ws + 104616960);
    unsigned short* Wpack = (unsigned short*)(ws + 105179136);  // 512 KB
    (void)in_sizes; (void)n_in; (void)out_size; (void)ws_size;

    const int O_Wl1 = 0,      O_bl1 = 16384,  O_Wr1 = 16512;
    const int O_Wl2 = 32896,  O_bl2 = 49280,  O_Wr2 = 49408;
    const int O_Wl3 = 65792,  O_bl3 = 82176,  O_Wr3 = 82304;
    const int O_Wl4 = 98688,  O_bl4 = 115072, O_Wr4 = 115200;
    const int O_Pr1 = 131584, O_pb1 = 131712, O_Po1 = 131713;
    const int O_Pr2 = 131841, O_pb2 = 131969, O_Po2 = 131970;
    const int O_W5  = 132098, O_b5  = 140290, O_W6 = 140354, O_b6 = 140482;

    CvtDesc d;
    const int srcIdx[22] = {4,5,6,7,8,9,10,11,12,13,14,15,16,17,18,19,20,21,22,23,24,25};
    const int nelems[22] = {16384,128,16384, 16384,128,16384, 16384,128,16384, 16384,128,16384,
                            128,1,128, 128,1,128, 8192,64,128,2};
    const int offs[22]   = {O_Wl1,O_bl1,O_Wr1, O_Wl2,O_bl2,O_Wr2, O_Wl3,O_bl3,O_Wr3, O_Wl4,O_bl4,O_Wr4,
                            O_Pr1,O_pb1,O_Po1, O_Pr2,O_pb2,O_Po2, O_W5,O_b5,O_W6,O_b6};
    for (int i = 0; i < 22; ++i) { d.src[i] = d_in[srcIdx[i]]; d.n[i] = nelems[i]; d.off[i] = offs[i]; }

    hipMemsetAsync(rowc, 0, NT * 4, stream);
    hipMemsetAsync(fill, 0, NT * 4, stream);
    hipMemsetAsync(g, 0, (NG * HID + NG + 512) * 4, stream);

    k_detect <<<1, 256, 0, stream>>>((const unsigned short*)x, flag);
    k_cvt    <<<dim3(64, 22), 256, 0, stream>>>(d, wts, flag);
    k_packW  <<<512, 256, 0, stream>>>(wts, make_int4(O_Wl1, O_Wl2, O_Wl3, O_Wl4),
                                       make_int4(O_Wr1, O_Wr2, O_Wr3, O_Wr4), Wpack);
    k_load_x <<<8192, 256, 0, stream>>>(x, hA, flag, NT * HID / 4);
    k_init_nm<<<256, 256, 0, stream>>>(nm);

    k_hist   <<<2048, 256, 0, stream>>>(dstE, rowc);
    k_scan1  <<<256, 256, 0, stream>>>(rowc, rp, bsum);
    k_scan2  <<<1, 256, 0, stream>>>(bsum, boff);
    k_scan3  <<<256, 256, 0, stream>>>(rp, boff);
    k_scatter<<<2048, 256, 0, stream>>>(srcE, dstE, rp, fill, col);
    k_invc   <<<256, 256, 0, stream>>>(nm, rp, col, invc);

    // layer 1: hA -> hB
    k_sage_fused<<<2048, 256, 0, stream>>>(hA, nullptr, nm, invc, rp, col, Wpack + 0 * 65536, wts + O_bl1, hB);
    // layer 2: hB -> hA
    k_sage_fused<<<2048, 256, 0, stream>>>(hB, nullptr, nm, invc, rp, col, Wpack + 1 * 65536, wts + O_bl2, hA);

    // pool 1 (k = 1024)
    k_node_dots<<<16384, 256, 0, stream>>>(hA, wts + O_Pr1, wts + O_Po1, q, r);
    k_score    <<<256, 256, 0, stream>>>(q, r, wts + O_pb1, rp, col, score);
    k_topk     <<<32, 1024, 0, stream>>>(score, nm, tvec, 1024);
    k_invc     <<<256, 256, 0, stream>>>(nm, rp, col, invc);

    // layer 3: hA (scaled by tvec on the fly) -> hB
    k_sage_fused<<<2048, 256, 0, stream>>>(hA, tvec, nm, invc, rp, col, Wpack + 2 * 65536, wts + O_bl3, hB);
    // layer 4: hB -> hA
    k_sage_fused<<<2048, 256, 0, stream>>>(hB, nullptr, nm, invc, rp, col, Wpack + 3 * 65536, wts + O_bl4, hA);

    // pool 2 (k = 512)
    k_node_dots<<<16384, 256, 0, stream>>>(hA, wts + O_Pr2, wts + O_Po2, q, r);
    k_score    <<<256, 256, 0, stream>>>(q, r, wts + O_pb2, rp, col, score);
    k_topk     <<<32, 1024, 0, stream>>>(score, nm, tvec, 512);

    // readout (h*t folded in)
    k_gsum<<<256, 256, 0, stream>>>(hA, tvec, nm, g, gcnt);
    k_gdiv<<<16, 256, 0, stream>>>(g, gcnt);
    k_mlp <<<32, 64, 0, stream>>>(g, wts + O_W5, wts + O_b5, wts + O_W6, wts + O_b6, d_out, flag);
}